// Round 4
// baseline (351.933 us; speedup 1.0000x reference)
//
#include <hip/hip_runtime.h>

typedef __attribute__((ext_vector_type(8))) short bf16x8;
typedef __attribute__((ext_vector_type(4))) float f32x4;

__device__ __forceinline__ float leaky(float v) { return fmaxf(v, 0.01f * v); }

__device__ __forceinline__ float bf2f(short s) {
    return __uint_as_float(((unsigned int)(unsigned short)s) << 16);
}

__device__ __forceinline__ unsigned short f2bf(float a) {
    unsigned int u = __float_as_uint(a);
    return (unsigned short)((u + 0x7FFFu + ((u >> 16) & 1u)) >> 16);
}

__device__ __forceinline__ unsigned int pk_bf16(float a, float b) {
    unsigned int ua = __float_as_uint(a);
    ua = (ua + 0x7FFFu + ((ua >> 16) & 1u)) >> 16;
    unsigned int ub = __float_as_uint(b);
    ub = (ub + 0x7FFFu + ((ub >> 16) & 1u)) >> 16;
    return ua | (ub << 16);
}

// Wb[n][k] = bf16(W[k][n])  (B^T layout for MFMA B-fragments)
__global__ __launch_bounds__(128) void prep_wb(const float* __restrict__ W,
                                               unsigned short* __restrict__ Wb) {
    int k = blockIdx.x;
    int n = threadIdx.x;
    Wb[n * 128 + k] = f2bf(W[k * 128 + n]);
}

#define PITCH 136  // bf16 elems per LDS row

// out[r][:] = bf16(h[r][:] @ W + b) via bf16 MFMA, fp32 accumulate.
// block = 256 threads = 4 waves; 128 rows/block; wave w: rows [32w, 32w+32).
__global__ __launch_bounds__(256, 4) void node_mfma(const float* __restrict__ h,
                                                    const unsigned short* __restrict__ Wb,
                                                    const float* __restrict__ b,
                                                    unsigned short* __restrict__ out, int N) {
    __shared__ unsigned short xt[128 * PITCH];
    int t = threadIdx.x;
    int r0 = blockIdx.x * 128;
    int s = t & 15;
    int el0 = t >> 4;
#pragma unroll
    for (int pass = 0; pass < 8; ++pass) {
        int el = pass * 16 + el0;
        int row = min(r0 + el, N - 1);
        const f32x4* hp = (const f32x4*)(h + (size_t)row * 128);
        f32x4 a0 = hp[s];
        f32x4 a1 = hp[s + 16];
        unsigned int* rp = (unsigned int*)(xt + el * PITCH);
        rp[2 * s]          = pk_bf16(a0.x, a0.y);
        rp[2 * s + 1]      = pk_bf16(a0.z, a0.w);
        rp[32 + 2 * s]     = pk_bf16(a1.x, a1.y);
        rp[32 + 2 * s + 1] = pk_bf16(a1.z, a1.w);
    }
    __syncthreads();

    int wave = t >> 6;
    int lane = t & 63;
    int m0 = wave * 32;
    int col = lane & 15;
    int quad = lane >> 4;

    f32x4 acc[2][8];
#pragma unroll
    for (int mt = 0; mt < 2; ++mt)
#pragma unroll
        for (int nt = 0; nt < 8; ++nt) acc[mt][nt] = (f32x4){0.f, 0.f, 0.f, 0.f};

#pragma unroll
    for (int k0 = 0; k0 < 128; k0 += 32) {
        bf16x8 afr[2];
#pragma unroll
        for (int mt = 0; mt < 2; ++mt)
            afr[mt] = *(const bf16x8*)(xt + (m0 + mt * 16 + col) * PITCH + k0 + quad * 8);
#pragma unroll
        for (int nt = 0; nt < 8; ++nt) {
            bf16x8 bfr = *(const bf16x8*)(Wb + (nt * 16 + col) * 128 + k0 + quad * 8);
            acc[0][nt] = __builtin_amdgcn_mfma_f32_16x16x32_bf16(afr[0], bfr, acc[0][nt], 0, 0, 0);
            acc[1][nt] = __builtin_amdgcn_mfma_f32_16x16x32_bf16(afr[1], bfr, acc[1][nt], 0, 0, 0);
        }
    }

#pragma unroll
    for (int nt = 0; nt < 8; ++nt) {
        float bb = b[nt * 16 + col];
#pragma unroll
        for (int mt = 0; mt < 2; ++mt)
#pragma unroll
            for (int rr = 0; rr < 4; ++rr) {
                int row = r0 + m0 + mt * 16 + quad * 4 + rr;
                if (row < N) out[(size_t)row * 128 + nt * 16 + col] = f2bf(acc[mt][nt][rr] + bb);
            }
    }
}

// LDS-free edge kernel: gather bf16 rows straight into MFMA A-fragments.
// Block = 256 = 4 waves; wave handles 32 edges; lane (col,quad) loads
// u/i segments [k0+8q .. +8) of rows e0+col and e0+16+col directly.
__global__ __launch_bounds__(256, 3) void edge_kernel(
    const unsigned short* __restrict__ u_f, const unsigned short* __restrict__ i_f,
    const int* __restrict__ src, const int* __restrict__ dst,
    const unsigned short* __restrict__ Wb,  // bf16 [n][k]
    const float* __restrict__ b1, const float* __restrict__ W2,
    const float* __restrict__ b2, float* __restrict__ out, int E) {
    int t = threadIdx.x;
    int wave = t >> 6;
    int lane = t & 63;
    int col = lane & 15;
    int quad = lane >> 4;
    int e0 = blockIdx.x * 128 + wave * 32;

    int ea = min(e0 + col, E - 1);
    int eb = min(e0 + 16 + col, E - 1);
    const unsigned short* ua = u_f + (size_t)src[ea] * 128 + quad * 8;
    const unsigned short* ia = i_f + (size_t)dst[ea] * 128 + quad * 8;
    const unsigned short* ub = u_f + (size_t)src[eb] * 128 + quad * 8;
    const unsigned short* ib = i_f + (size_t)dst[eb] * 128 + quad * 8;

    // ---- gather raw segments (16 x 16B loads, max MLP) ----
    bf16x8 ru[2][4], ri[2][4];
#pragma unroll
    for (int k = 0; k < 4; ++k) {
        ru[0][k] = *(const bf16x8*)(ua + 32 * k);
        ri[0][k] = *(const bf16x8*)(ia + 32 * k);
        ru[1][k] = *(const bf16x8*)(ub + 32 * k);
        ri[1][k] = *(const bf16x8*)(ib + 32 * k);
    }

    // ---- x = bf16(leaky(u + i)) in registers ----
    bf16x8 afr[2][4];
#pragma unroll
    for (int mt = 0; mt < 2; ++mt)
#pragma unroll
        for (int k = 0; k < 4; ++k) {
            bf16x8 u8 = ru[mt][k];
            bf16x8 i8 = ri[mt][k];
            bf16x8 a;
#pragma unroll
            for (int j = 0; j < 8; j += 2) {
                float x0 = leaky(bf2f(u8[j])     + bf2f(i8[j]));
                float x1 = leaky(bf2f(u8[j + 1]) + bf2f(i8[j + 1]));
                unsigned int p = pk_bf16(x0, x1);
                a[j]     = (short)(p & 0xFFFFu);
                a[j + 1] = (short)(p >> 16);
            }
            afr[mt][k] = a;
        }

    // ---- MFMA: 32 edges x 128 cols ----
    f32x4 acc[2][8];
#pragma unroll
    for (int mt = 0; mt < 2; ++mt)
#pragma unroll
        for (int nt = 0; nt < 8; ++nt) acc[mt][nt] = (f32x4){0.f, 0.f, 0.f, 0.f};

#pragma unroll
    for (int k = 0; k < 4; ++k) {
#pragma unroll
        for (int nt = 0; nt < 8; ++nt) {
            bf16x8 bfr = *(const bf16x8*)(Wb + (nt * 16 + col) * 128 + 32 * k + quad * 8);
            acc[0][nt] = __builtin_amdgcn_mfma_f32_16x16x32_bf16(afr[0][k], bfr, acc[0][nt], 0, 0, 0);
            acc[1][nt] = __builtin_amdgcn_mfma_f32_16x16x32_bf16(afr[1][k], bfr, acc[1][nt], 0, 0, 0);
        }
    }

    // ---- epilogue: z[m] = sum_n leaky(y+b1[n])*W2[n]; out = leaky(z+b2) ----
    float p[2][4];
#pragma unroll
    for (int mt = 0; mt < 2; ++mt)
#pragma unroll
        for (int rr = 0; rr < 4; ++rr) p[mt][rr] = 0.f;

#pragma unroll
    for (int nt = 0; nt < 8; ++nt) {
        int n = nt * 16 + col;
        float bb = b1[n];
        float ww = W2[n];
#pragma unroll
        for (int mt = 0; mt < 2; ++mt)
#pragma unroll
            for (int rr = 0; rr < 4; ++rr) {
                float y = acc[mt][nt][rr] + bb;
                p[mt][rr] += leaky(y) * ww;
            }
    }
#pragma unroll
    for (int off = 1; off < 16; off <<= 1)
#pragma unroll
        for (int mt = 0; mt < 2; ++mt)
#pragma unroll
            for (int rr = 0; rr < 4; ++rr)
                p[mt][rr] += __shfl_xor(p[mt][rr], off, 64);

    if (col == 0) {
        float bias2 = b2[0];
#pragma unroll
        for (int mt = 0; mt < 2; ++mt)
#pragma unroll
            for (int rr = 0; rr < 4; ++rr) {
                int e = e0 + mt * 16 + quad * 4 + rr;
                if (e < E) out[e] = leaky(p[mt][rr] + bias2);
            }
    }
}

extern "C" void kernel_launch(void* const* d_in, const int* in_sizes, int n_in,
                              void* d_out, int out_size, void* d_ws, size_t ws_size,
                              hipStream_t stream) {
    const float* h_user  = (const float*)d_in[0];
    const float* h_item  = (const float*)d_in[1];
    const int*   src_idx = (const int*)d_in[2];
    const int*   dst_idx = (const int*)d_in[3];
    const float* W_left  = (const float*)d_in[4];
    const float* b_left  = (const float*)d_in[5];
    const float* W_right = (const float*)d_in[6];
    const float* b_right = (const float*)d_in[7];
    const float* W1      = (const float*)d_in[8];
    const float* b1      = (const float*)d_in[9];
    const float* W2      = (const float*)d_in[10];
    const float* b2      = (const float*)d_in[11];
    float* out = (float*)d_out;

    int N_U = in_sizes[0] / 128;
    int N_I = in_sizes[1] / 128;
    int E   = in_sizes[2];

    // Workspace: [Wb1 32KB][WLb 32KB][WRb 32KB][pad to 128KB][u_f bf16][i_f bf16]
    unsigned short* Wb1 = (unsigned short*)d_ws;
    unsigned short* WLb = Wb1 + 16384;
    unsigned short* WRb = WLb + 16384;
    unsigned short* u_f = (unsigned short*)((char*)d_ws + 131072);
    unsigned short* i_f = u_f + (size_t)N_U * 128;

    prep_wb<<<128, 128, 0, stream>>>(W1, Wb1);
    prep_wb<<<128, 128, 0, stream>>>(W_left, WLb);
    prep_wb<<<128, 128, 0, stream>>>(W_right, WRb);

    node_mfma<<<(N_U + 127) / 128, 256, 0, stream>>>(h_user, WLb, b_left, u_f, N_U);
    node_mfma<<<(N_I + 127) / 128, 256, 0, stream>>>(h_item, WRb, b_right, i_f, N_I);

    edge_kernel<<<(E + 127) / 128, 256, 0, stream>>>(u_f, i_f, src_idx, dst_idx,
                                                     Wb1, b1, W2, b2, out, E);
}

// Round 5
// 300.189 us; speedup vs baseline: 1.1724x; 1.1724x over previous
//
#include <hip/hip_runtime.h>

typedef __attribute__((ext_vector_type(8))) short bf16x8;
typedef __attribute__((ext_vector_type(4))) float f32x4;

__device__ __forceinline__ float leaky(float v) { return fmaxf(v, 0.01f * v); }

__device__ __forceinline__ float bf2f(short s) {
    return __uint_as_float(((unsigned int)(unsigned short)s) << 16);
}

__device__ __forceinline__ unsigned short f2bf(float a) {
    unsigned int u = __float_as_uint(a);
    return (unsigned short)((u + 0x7FFFu + ((u >> 16) & 1u)) >> 16);
}

__device__ __forceinline__ unsigned int pk_bf16(float a, float b) {
    unsigned int ua = __float_as_uint(a);
    ua = (ua + 0x7FFFu + ((ua >> 16) & 1u)) >> 16;
    unsigned int ub = __float_as_uint(b);
    ub = (ub + 0x7FFFu + ((ub >> 16) & 1u)) >> 16;
    return ua | (ub << 16);
}

// Merged weight prep:
//  blocks [0,128):   WLb[n][k] = bf16(W_left[k][n])   (row layout, node kernel)
//  blocks [128,256): WRb[n][k] = bf16(W_right[k][n])
//  blocks [256,384): Wf = W1 in MFMA B-fragment order: for (kb,nt,lane,j):
//                    Wf[((kb*8+nt)*64+lane)*8+j] = bf16(W1[kb*32+(lane>>4)*8+j][nt*16+(lane&15)])
__global__ __launch_bounds__(128) void prep(const float* __restrict__ WL,
                                            const float* __restrict__ WR,
                                            const float* __restrict__ W1,
                                            unsigned short* __restrict__ WLb,
                                            unsigned short* __restrict__ WRb,
                                            unsigned short* __restrict__ Wf) {
    int g = blockIdx.x;
    int t = threadIdx.x;
    if (g < 128) {
        WLb[t * 128 + g] = f2bf(WL[g * 128 + t]);
    } else if (g < 256) {
        int k = g - 128;
        WRb[t * 128 + k] = f2bf(WR[k * 128 + t]);
    } else {
        int f = (g - 256) * 128 + t;
        int j = f & 7, lane = (f >> 3) & 63, nt = (f >> 9) & 7, kb = f >> 12;
        int n = nt * 16 + (lane & 15);
        int k = kb * 32 + (lane >> 4) * 8 + j;
        Wf[f] = f2bf(W1[k * 128 + n]);
    }
}

#define PITCH 136  // bf16 elems per LDS row

// Both node linears in one launch: out = bf16(h @ W + b) via bf16 MFMA.
// block = 256 threads = 4 waves; 128 rows/block.
__global__ __launch_bounds__(256, 4) void node_mfma2(const float* __restrict__ h_user,
                                                     const float* __restrict__ h_item,
                                                     const unsigned short* __restrict__ WLb,
                                                     const unsigned short* __restrict__ WRb,
                                                     const float* __restrict__ b_left,
                                                     const float* __restrict__ b_right,
                                                     unsigned short* __restrict__ u_f,
                                                     unsigned short* __restrict__ i_f,
                                                     int N_U, int N_I, int BU) {
    bool isU = (int)blockIdx.x < BU;
    const float* h = isU ? h_user : h_item;
    const unsigned short* Wb = isU ? WLb : WRb;
    const float* b = isU ? b_left : b_right;
    unsigned short* out = isU ? u_f : i_f;
    int N = isU ? N_U : N_I;
    int r0 = (isU ? blockIdx.x : blockIdx.x - BU) * 128;

    __shared__ unsigned short xt[128 * PITCH];
    int t = threadIdx.x;
    int s = t & 15;
    int el0 = t >> 4;
#pragma unroll
    for (int pass = 0; pass < 8; ++pass) {
        int el = pass * 16 + el0;
        int row = min(r0 + el, N - 1);
        const f32x4* hp = (const f32x4*)(h + (size_t)row * 128);
        f32x4 a0 = hp[s];
        f32x4 a1 = hp[s + 16];
        unsigned int* rp = (unsigned int*)(xt + el * PITCH);
        rp[2 * s]          = pk_bf16(a0.x, a0.y);
        rp[2 * s + 1]      = pk_bf16(a0.z, a0.w);
        rp[32 + 2 * s]     = pk_bf16(a1.x, a1.y);
        rp[32 + 2 * s + 1] = pk_bf16(a1.z, a1.w);
    }
    __syncthreads();

    int wave = t >> 6;
    int lane = t & 63;
    int m0 = wave * 32;
    int col = lane & 15;
    int quad = lane >> 4;

    f32x4 acc[2][8];
#pragma unroll
    for (int mt = 0; mt < 2; ++mt)
#pragma unroll
        for (int nt = 0; nt < 8; ++nt) acc[mt][nt] = (f32x4){0.f, 0.f, 0.f, 0.f};

#pragma unroll
    for (int k0 = 0; k0 < 128; k0 += 32) {
        bf16x8 afr[2];
#pragma unroll
        for (int mt = 0; mt < 2; ++mt)
            afr[mt] = *(const bf16x8*)(xt + (m0 + mt * 16 + col) * PITCH + k0 + quad * 8);
#pragma unroll
        for (int nt = 0; nt < 8; ++nt) {
            bf16x8 bfr = *(const bf16x8*)(Wb + (nt * 16 + col) * 128 + k0 + quad * 8);
            acc[0][nt] = __builtin_amdgcn_mfma_f32_16x16x32_bf16(afr[0], bfr, acc[0][nt], 0, 0, 0);
            acc[1][nt] = __builtin_amdgcn_mfma_f32_16x16x32_bf16(afr[1], bfr, acc[1][nt], 0, 0, 0);
        }
    }

#pragma unroll
    for (int nt = 0; nt < 8; ++nt) {
        float bb = b[nt * 16 + col];
#pragma unroll
        for (int mt = 0; mt < 2; ++mt)
#pragma unroll
            for (int rr = 0; rr < 4; ++rr) {
                int row = r0 + m0 + mt * 16 + quad * 4 + rr;
                if (row < N) out[(size_t)row * 128 + nt * 16 + col] = f2bf(acc[mt][nt][rr] + bb);
            }
    }
}

// Edge kernel: 512 threads = 8 waves, 128 edges/block.
// Stage: gather bf16 u/i segments -> x = bf16(leaky(u+i)) -> LDS tile.
// MFMA: wave w does rows [16w,16w+16) x 128 cols; B from fragment-ordered Wf
// (contiguous 1KB wave loads). Fused leaky/b1/W2/b2 epilogue.
#define TE 128

__global__ __launch_bounds__(512, 8) void edge_kernel(
    const unsigned short* __restrict__ u_f, const unsigned short* __restrict__ i_f,
    const int* __restrict__ src, const int* __restrict__ dst,
    const unsigned short* __restrict__ Wf,
    const float* __restrict__ b1, const float* __restrict__ W2,
    const float* __restrict__ b2, float* __restrict__ out, int E) {
    __shared__ unsigned short xt[TE * PITCH];
    int t = threadIdx.x;
    int e0 = blockIdx.x * TE;

    // ---- stage: 16 threads per edge (one 8-elem segment each), 4 passes ----
    int s = t & 15;
    int el0 = t >> 4;  // 0..31
#pragma unroll
    for (int pass = 0; pass < 4; ++pass) {
        int el = pass * 32 + el0;
        int ec = min(e0 + el, E - 1);
        bf16x8 u8 = *(const bf16x8*)(u_f + (size_t)src[ec] * 128 + s * 8);
        bf16x8 i8 = *(const bf16x8*)(i_f + (size_t)dst[ec] * 128 + s * 8);
        bf16x8 a;
#pragma unroll
        for (int j = 0; j < 8; j += 2) {
            float x0 = leaky(bf2f(u8[j])     + bf2f(i8[j]));
            float x1 = leaky(bf2f(u8[j + 1]) + bf2f(i8[j + 1]));
            unsigned int p = pk_bf16(x0, x1);
            a[j]     = (short)(p & 0xFFFFu);
            a[j + 1] = (short)(p >> 16);
        }
        *(bf16x8*)(xt + el * PITCH + s * 8) = a;
    }
    __syncthreads();

    // ---- MFMA: wave handles 16 edges x 128 cols ----
    int wave = t >> 6;
    int lane = t & 63;
    int col = lane & 15;
    int quad = lane >> 4;
    int m0 = wave * 16;

    f32x4 acc[8];
#pragma unroll
    for (int nt = 0; nt < 8; ++nt) acc[nt] = (f32x4){0.f, 0.f, 0.f, 0.f};

#pragma unroll
    for (int kb = 0; kb < 4; ++kb) {
        bf16x8 afr = *(const bf16x8*)(xt + (m0 + col) * PITCH + kb * 32 + quad * 8);
#pragma unroll
        for (int nt = 0; nt < 8; ++nt) {
            bf16x8 bfr = *(const bf16x8*)(Wf + ((kb * 8 + nt) * 64 + lane) * 8);
            acc[nt] = __builtin_amdgcn_mfma_f32_16x16x32_bf16(afr, bfr, acc[nt], 0, 0, 0);
        }
    }

    // ---- epilogue: z[m] = sum_n leaky(y+b1[n])*W2[n]; out = leaky(z+b2) ----
    float p[4] = {0.f, 0.f, 0.f, 0.f};
#pragma unroll
    for (int nt = 0; nt < 8; ++nt) {
        int n = nt * 16 + col;
        float bb = b1[n];
        float ww = W2[n];
#pragma unroll
        for (int rr = 0; rr < 4; ++rr) p[rr] += leaky(acc[nt][rr] + bb) * ww;
    }
#pragma unroll
    for (int off = 1; off < 16; off <<= 1)
#pragma unroll
        for (int rr = 0; rr < 4; ++rr) p[rr] += __shfl_xor(p[rr], off, 64);

    if (col == 0) {
        float bias2 = b2[0];
#pragma unroll
        for (int rr = 0; rr < 4; ++rr) {
            int e = e0 + m0 + quad * 4 + rr;
            if (e < E) out[e] = leaky(p[rr] + bias2);
        }
    }
}

extern "C" void kernel_launch(void* const* d_in, const int* in_sizes, int n_in,
                              void* d_out, int out_size, void* d_ws, size_t ws_size,
                              hipStream_t stream) {
    const float* h_user  = (const float*)d_in[0];
    const float* h_item  = (const float*)d_in[1];
    const int*   src_idx = (const int*)d_in[2];
    const int*   dst_idx = (const int*)d_in[3];
    const float* W_left  = (const float*)d_in[4];
    const float* b_left  = (const float*)d_in[5];
    const float* W_right = (const float*)d_in[6];
    const float* b_right = (const float*)d_in[7];
    const float* W1      = (const float*)d_in[8];
    const float* b1      = (const float*)d_in[9];
    const float* W2      = (const float*)d_in[10];
    const float* b2      = (const float*)d_in[11];
    float* out = (float*)d_out;

    int N_U = in_sizes[0] / 128;
    int N_I = in_sizes[1] / 128;
    int E   = in_sizes[2];

    // Workspace: [Wf 32KB][WLb 32KB][WRb 32KB][pad to 128KB][u_f bf16][i_f bf16]
    unsigned short* Wf  = (unsigned short*)d_ws;
    unsigned short* WLb = Wf + 16384;
    unsigned short* WRb = WLb + 16384;
    unsigned short* u_f = (unsigned short*)((char*)d_ws + 131072);
    unsigned short* i_f = u_f + (size_t)N_U * 128;

    prep<<<384, 128, 0, stream>>>(W_left, W_right, W1, WLb, WRb, Wf);

    int BU = (N_U + 127) / 128;
    int BI = (N_I + 127) / 128;
    node_mfma2<<<BU + BI, 256, 0, stream>>>(h_user, h_item, WLb, WRb, b_left, b_right,
                                            u_f, i_f, N_U, N_I, BU);

    edge_kernel<<<(E + TE - 1) / TE, 512, 0, stream>>>(u_f, i_f, src_idx, dst_idx,
                                                       Wf, b1, W2, b2, out, E);
}

// Round 6
// 232.987 us; speedup vs baseline: 1.5105x; 1.2884x over previous
//
#include <hip/hip_runtime.h>

typedef __attribute__((ext_vector_type(8))) short bf16x8;
typedef __attribute__((ext_vector_type(4))) float f32x4;

__device__ __forceinline__ float leaky(float v) { return fmaxf(v, 0.01f * v); }

__device__ __forceinline__ float bf2f(short s) {
    return __uint_as_float(((unsigned int)(unsigned short)s) << 16);
}

__device__ __forceinline__ unsigned short f2bf(float a) {
    unsigned int u = __float_as_uint(a);
    return (unsigned short)((u + 0x7FFFu + ((u >> 16) & 1u)) >> 16);
}

__device__ __forceinline__ unsigned int pk_bf16(float a, float b) {
    unsigned int ua = __float_as_uint(a);
    ua = (ua + 0x7FFFu + ((ua >> 16) & 1u)) >> 16;
    unsigned int ub = __float_as_uint(b);
    ub = (ub + 0x7FFFu + ((ub >> 16) & 1u)) >> 16;
    return ua | (ub << 16);
}

// Weight prep, all in MFMA B-fragment order:
//   frag index f: j=f&7, lane=(f>>3)&63, nt=(f>>9)&7, kb=f>>12
//   n = nt*16 + (lane&15), k_frag = kb*32 + (lane>>4)*8 + j
// blocks [0,128):   WLf[f] = bf16(W_left[k_frag][n])
// blocks [128,256): WRf[f] = bf16(W_right[k_frag][n])
// blocks [256,384): Wf[f]  = bf16(W1[phi(k_frag)][n]), phi(p) = (p&7)*16 + (p>>3)
//   (phi = the feature order node_mfma2 stores u_f/i_f in; elementwise ops
//    between node output and edge GEMM input commute with phi.)
__global__ __launch_bounds__(128) void prep(const float* __restrict__ WL,
                                            const float* __restrict__ WR,
                                            const float* __restrict__ W1,
                                            unsigned short* __restrict__ WLf,
                                            unsigned short* __restrict__ WRf,
                                            unsigned short* __restrict__ Wf) {
    int g = blockIdx.x;
    int f = (g & 127) * 128 + threadIdx.x;
    int j = f & 7, lane = (f >> 3) & 63, nt = (f >> 9) & 7, kb = f >> 12;
    int n = nt * 16 + (lane & 15);
    int kf = kb * 32 + (lane >> 4) * 8 + j;
    if (g < 128) {
        WLf[f] = f2bf(WL[kf * 128 + n]);
    } else if (g < 256) {
        WRf[f] = f2bf(WR[kf * 128 + n]);
    } else {
        int k = (kf & 7) * 16 + (kf >> 3);  // phi
        Wf[f] = f2bf(W1[k * 128 + n]);
    }
}

#define PITCH 136  // bf16 elems per LDS row

// Both node linears in one launch: out = bf16(h @ W + b), stored in phi-order:
// stored position p = col*8 + nt holds logical feature n = nt*16 + col, so each
// lane's 8 nt-values for one row are a single contiguous 16B store.
__global__ __launch_bounds__(256, 4) void node_mfma2(const float* __restrict__ h_user,
                                                     const float* __restrict__ h_item,
                                                     const unsigned short* __restrict__ WLf,
                                                     const unsigned short* __restrict__ WRf,
                                                     const float* __restrict__ b_left,
                                                     const float* __restrict__ b_right,
                                                     unsigned short* __restrict__ u_f,
                                                     unsigned short* __restrict__ i_f,
                                                     int N_U, int N_I, int BU) {
    bool isU = (int)blockIdx.x < BU;
    const float* h = isU ? h_user : h_item;
    const unsigned short* Wfr = isU ? WLf : WRf;
    const float* b = isU ? b_left : b_right;
    unsigned short* out = isU ? u_f : i_f;
    int N = isU ? N_U : N_I;
    int r0 = (isU ? blockIdx.x : blockIdx.x - BU) * 128;

    __shared__ unsigned short xt[128 * PITCH];
    int t = threadIdx.x;
    int s = t & 15;
    int el0 = t >> 4;
#pragma unroll
    for (int pass = 0; pass < 8; ++pass) {
        int el = pass * 16 + el0;
        int row = min(r0 + el, N - 1);
        const f32x4* hp = (const f32x4*)(h + (size_t)row * 128);
        f32x4 a0 = hp[s];
        f32x4 a1 = hp[s + 16];
        unsigned int* rp = (unsigned int*)(xt + el * PITCH);
        rp[2 * s]          = pk_bf16(a0.x, a0.y);
        rp[2 * s + 1]      = pk_bf16(a0.z, a0.w);
        rp[32 + 2 * s]     = pk_bf16(a1.x, a1.y);
        rp[32 + 2 * s + 1] = pk_bf16(a1.z, a1.w);
    }
    __syncthreads();

    int wave = t >> 6;
    int lane = t & 63;
    int m0 = wave * 32;
    int col = lane & 15;
    int quad = lane >> 4;

    f32x4 acc[2][8];
#pragma unroll
    for (int mt = 0; mt < 2; ++mt)
#pragma unroll
        for (int nt = 0; nt < 8; ++nt) acc[mt][nt] = (f32x4){0.f, 0.f, 0.f, 0.f};

#pragma unroll
    for (int kb = 0; kb < 4; ++kb) {
        bf16x8 afr[2];
#pragma unroll
        for (int mt = 0; mt < 2; ++mt)
            afr[mt] = *(const bf16x8*)(xt + (m0 + mt * 16 + col) * PITCH + kb * 32 + quad * 8);
#pragma unroll
        for (int nt = 0; nt < 8; ++nt) {
            bf16x8 bfr = *(const bf16x8*)(Wfr + ((kb * 8 + nt) * 64 + lane) * 8);
            acc[0][nt] = __builtin_amdgcn_mfma_f32_16x16x32_bf16(afr[0], bfr, acc[0][nt], 0, 0, 0);
            acc[1][nt] = __builtin_amdgcn_mfma_f32_16x16x32_bf16(afr[1], bfr, acc[1][nt], 0, 0, 0);
        }
    }

    // epilogue: per (mt,rr) pack the 8 nt-values -> one 16B store at col*8
#pragma unroll
    for (int mt = 0; mt < 2; ++mt)
#pragma unroll
        for (int rr = 0; rr < 4; ++rr) {
            int row = r0 + m0 + mt * 16 + quad * 4 + rr;
            bf16x8 v;
#pragma unroll
            for (int nt = 0; nt < 8; ++nt)
                v[nt] = (short)f2bf(acc[mt][nt][rr] + b[nt * 16 + col]);
            if (row < N) *(bf16x8*)(out + (size_t)row * 128 + col * 8) = v;
        }
}

// Edge kernel: 512 threads = 8 waves, 128 edges/block, col-split wave pairs.
// Wave w: edges [32*(w>>1), +32), cols [64*(w&1), +64)  -> B-traffic halved.
#define TE 128

__global__ __launch_bounds__(512, 8) void edge_kernel(
    const unsigned short* __restrict__ u_f, const unsigned short* __restrict__ i_f,
    const int* __restrict__ src, const int* __restrict__ dst,
    const unsigned short* __restrict__ Wf,
    const float* __restrict__ b1, const float* __restrict__ W2,
    const float* __restrict__ b2, float* __restrict__ out, int E) {
    __shared__ unsigned short xt[TE * PITCH];
    __shared__ float zb[4][2][32];
    int t = threadIdx.x;
    int e0 = blockIdx.x * TE;

    // ---- stage: 16 threads per edge (one 8-elem segment each), 4 passes ----
    int s = t & 15;
    int el0 = t >> 4;  // 0..31
#pragma unroll
    for (int pass = 0; pass < 4; ++pass) {
        int el = pass * 32 + el0;
        int ec = min(e0 + el, E - 1);
        bf16x8 u8 = *(const bf16x8*)(u_f + (size_t)src[ec] * 128 + s * 8);
        bf16x8 i8 = *(const bf16x8*)(i_f + (size_t)dst[ec] * 128 + s * 8);
        bf16x8 a;
#pragma unroll
        for (int j = 0; j < 8; j += 2) {
            float x0 = leaky(bf2f(u8[j])     + bf2f(i8[j]));
            float x1 = leaky(bf2f(u8[j + 1]) + bf2f(i8[j + 1]));
            unsigned int p = pk_bf16(x0, x1);
            a[j]     = (short)(p & 0xFFFFu);
            a[j + 1] = (short)(p >> 16);
        }
        *(bf16x8*)(xt + el * PITCH + s * 8) = a;
    }
    __syncthreads();

    // ---- MFMA: wave handles 32 edges x 64 cols ----
    int wave = t >> 6;
    int lane = t & 63;
    int col = lane & 15;
    int quad = lane >> 4;
    int wp = wave >> 1;   // wave pair -> edge group
    int ch = wave & 1;    // col half
    int m0 = wp * 32;

    f32x4 acc[2][4];
#pragma unroll
    for (int mt = 0; mt < 2; ++mt)
#pragma unroll
        for (int i = 0; i < 4; ++i) acc[mt][i] = (f32x4){0.f, 0.f, 0.f, 0.f};

#pragma unroll
    for (int kb = 0; kb < 4; ++kb) {
        bf16x8 afr[2];
#pragma unroll
        for (int mt = 0; mt < 2; ++mt)
            afr[mt] = *(const bf16x8*)(xt + (m0 + mt * 16 + col) * PITCH + kb * 32 + quad * 8);
#pragma unroll
        for (int i = 0; i < 4; ++i) {
            int nt = ch * 4 + i;
            bf16x8 bfr = *(const bf16x8*)(Wf + ((kb * 8 + nt) * 64 + lane) * 8);
            acc[0][i] = __builtin_amdgcn_mfma_f32_16x16x32_bf16(afr[0], bfr, acc[0][i], 0, 0, 0);
            acc[1][i] = __builtin_amdgcn_mfma_f32_16x16x32_bf16(afr[1], bfr, acc[1][i], 0, 0, 0);
        }
    }

    // ---- epilogue: partial z over this wave's 64 cols ----
    float p[2][4];
#pragma unroll
    for (int mt = 0; mt < 2; ++mt)
#pragma unroll
        for (int rr = 0; rr < 4; ++rr) p[mt][rr] = 0.f;

#pragma unroll
    for (int i = 0; i < 4; ++i) {
        int n = (ch * 4 + i) * 16 + col;
        float bb = b1[n];
        float ww = W2[n];
#pragma unroll
        for (int mt = 0; mt < 2; ++mt)
#pragma unroll
            for (int rr = 0; rr < 4; ++rr) p[mt][rr] += leaky(acc[mt][i][rr] + bb) * ww;
    }
#pragma unroll
    for (int off = 1; off < 16; off <<= 1)
#pragma unroll
        for (int mt = 0; mt < 2; ++mt)
#pragma unroll
            for (int rr = 0; rr < 4; ++rr) p[mt][rr] += __shfl_xor(p[mt][rr], off, 64);

    if (col == 0) {
#pragma unroll
        for (int mt = 0; mt < 2; ++mt)
#pragma unroll
            for (int rr = 0; rr < 4; ++rr)
                zb[wp][ch][mt * 16 + quad * 4 + rr] = p[mt][rr];
    }
    __syncthreads();

    if (t < 128) {
        int g = t >> 5;       // wave pair
        int idx = t & 31;     // edge within pair
        float z = zb[g][0][idx] + zb[g][1][idx] + b2[0];
        int e = e0 + g * 32 + idx;
        if (e < E) out[e] = leaky(z);
    }
}

extern "C" void kernel_launch(void* const* d_in, const int* in_sizes, int n_in,
                              void* d_out, int out_size, void* d_ws, size_t ws_size,
                              hipStream_t stream) {
    const float* h_user  = (const float*)d_in[0];
    const float* h_item  = (const float*)d_in[1];
    const int*   src_idx = (const int*)d_in[2];
    const int*   dst_idx = (const int*)d_in[3];
    const float* W_left  = (const float*)d_in[4];
    const float* b_left  = (const float*)d_in[5];
    const float* W_right = (const float*)d_in[6];
    const float* b_right = (const float*)d_in[7];
    const float* W1      = (const float*)d_in[8];
    const float* b1      = (const float*)d_in[9];
    const float* W2      = (const float*)d_in[10];
    const float* b2      = (const float*)d_in[11];
    float* out = (float*)d_out;

    int N_U = in_sizes[0] / 128;
    int N_I = in_sizes[1] / 128;
    int E   = in_sizes[2];

    // Workspace: [Wf 32KB][WLf 32KB][WRf 32KB][pad to 128KB][u_f bf16][i_f bf16]
    unsigned short* Wf  = (unsigned short*)d_ws;
    unsigned short* WLf = Wf + 16384;
    unsigned short* WRf = WLf + 16384;
    unsigned short* u_f = (unsigned short*)((char*)d_ws + 131072);
    unsigned short* i_f = u_f + (size_t)N_U * 128;

    prep<<<384, 128, 0, stream>>>(W_left, W_right, W1, WLf, WRf, Wf);

    int BU = (N_U + 127) / 128;
    int BI = (N_I + 127) / 128;
    node_mfma2<<<BU + BI, 256, 0, stream>>>(h_user, h_item, WLf, WRf, b_left, b_right,
                                            u_f, i_f, N_U, N_I, BU);

    edge_kernel<<<(E + TE - 1) / TE, 512, 0, stream>>>(u_f, i_f, src_idx, dst_idx,
                                                       Wf, b1, W2, b2, out, E);
}